// Round 1
// baseline (356.228 us; speedup 1.0000x reference)
//
#include <hip/hip_runtime.h>
#include <hip/hip_bf16.h>
#include <stdint.h>

typedef __bf16 bf16x8 __attribute__((ext_vector_type(8)));
typedef float  f32x4  __attribute__((ext_vector_type(4)));
typedef short  short8 __attribute__((ext_vector_type(8)));
typedef short  short4v __attribute__((ext_vector_type(4)));
typedef float  float4v __attribute__((ext_vector_type(4)));

#define AS1 __attribute__((address_space(1)))
#define AS3 __attribute__((address_space(3)))

__device__ __forceinline__ void g2l16(const void* g, void* l) {
    __builtin_amdgcn_global_load_lds((const AS1 void*)g, (AS3 void*)l, 16, 0, 0);
}

__device__ __forceinline__ short f2bf(float f) {
    unsigned u = __builtin_bit_cast(unsigned, f);
    unsigned r = u + 0x7FFFu + ((u >> 16) & 1u);
    return (short)(r >> 16);
}

__device__ __forceinline__ bf16x8 ldb8(const short* p) {
    return __builtin_bit_cast(bf16x8, *(const short8*)p);
}

// ---------------- cast X fp32 -> bf16 ----------------
__global__ __launch_bounds__(256) void cast_x(const float* __restrict__ X,
                                              short* __restrict__ Xb) {
    int i = (blockIdx.x * 256 + threadIdx.x) * 4;
    float4v v = *(const float4v*)(X + i);
    short4v o;
    o[0] = f2bf(v[0]); o[1] = f2bf(v[1]); o[2] = f2bf(v[2]); o[3] = f2bf(v[3]);
    *(short4v*)(Xb + i) = o;
}

// ---------------- transpose weights: W[K][N] fp32 -> WT[N][K] bf16 ----------------
__global__ __launch_bounds__(256) void transpose_w(
    const float* __restrict__ W0, const float* __restrict__ W1,
    const float* __restrict__ W2, const float* __restrict__ W3,
    short* __restrict__ T0, short* __restrict__ T1,
    short* __restrict__ T2, short* __restrict__ T3) {
    int z = blockIdx.z;
    const float* W = z == 0 ? W0 : z == 1 ? W1 : z == 2 ? W2 : W3;
    short* T = z == 0 ? T0 : z == 1 ? T1 : z == 2 ? T2 : T3;
    __shared__ float t[32][33];
    int n0 = blockIdx.x * 32, k0 = blockIdx.y * 32;
    int tx = threadIdx.x & 31, ty = threadIdx.x >> 5;
#pragma unroll
    for (int i = 0; i < 4; i++)
        t[ty + i * 8][tx] = W[(size_t)(k0 + ty + i * 8) * 1024 + n0 + tx];
    __syncthreads();
#pragma unroll
    for (int i = 0; i < 4; i++)
        T[(size_t)(n0 + ty + i * 8) * 1024 + k0 + tx] = f2bf(t[tx][ty + i * 8]);
}

// ---------------- transpose V: Vb[B*S][E] -> VT[bh][64][S] ----------------
__global__ __launch_bounds__(256) void transpose_v(const short* __restrict__ Vb,
                                                   short* __restrict__ VT) {
    int bh = blockIdx.z;
    int b = bh >> 4, h = bh & 15;
    int d0 = blockIdx.y * 32;
    int s0 = blockIdx.x * 32;
    __shared__ short t[32][33];
    int tx = threadIdx.x & 31, ty = threadIdx.x >> 5;
#pragma unroll
    for (int i = 0; i < 4; i++)
        t[ty + i * 8][tx] = Vb[(size_t)(b * 2048 + s0 + ty + i * 8) * 1024 + h * 64 + d0 + tx];
    __syncthreads();
#pragma unroll
    for (int i = 0; i < 4; i++)
        VT[(size_t)(bh * 64 + d0 + ty + i * 8) * 2048 + s0 + tx] = t[tx][ty + i * 8];
}

// ---------------- fused QKV GEMM: Xb[4096][1024] @ W^T -> {Q,K,V}b bf16 ----------------
__global__ __launch_bounds__(256) void gemm_qkv(
    const short* __restrict__ Xb,
    const short* __restrict__ WqT, const short* __restrict__ WkT, const short* __restrict__ WvT,
    const float* __restrict__ bq, const float* __restrict__ bk, const float* __restrict__ bv,
    short* __restrict__ Qb, short* __restrict__ Kb, short* __restrict__ Vb) {
    const int K = 1024, N = 1024;
    int mt = blockIdx.x;
    int yy = blockIdx.y;
    int mat = yy >> 3, nt = yy & 7;
    const short* Bt = mat == 0 ? WqT : mat == 1 ? WkT : WvT;
    const float* bias = mat == 0 ? bq : mat == 1 ? bk : bv;
    short* Cout = mat == 0 ? Qb : mat == 1 ? Kb : Vb;

    int tid = threadIdx.x;
    int w = tid >> 6, lane = tid & 63;
    int quad = lane >> 4, l16 = lane & 15;
    int wy = w >> 1, wx = w & 1;

    __shared__ __align__(16) short A_lds[128 * 32];
    __shared__ __align__(16) short B_lds[128 * 32];

    f32x4 acc[4][4];
#pragma unroll
    for (int mi = 0; mi < 4; mi++)
#pragma unroll
        for (int ni = 0; ni < 4; ni++) acc[mi][ni] = (f32x4){0.f, 0.f, 0.f, 0.f};

    int m0 = mt * 128, n0 = nt * 128;
    for (int kt = 0; kt < 32; kt++) {
        __syncthreads();
#pragma unroll
        for (int c = 0; c < 2; c++) {
            int row = w * 32 + c * 16 + (lane >> 2);
            g2l16(Xb + (size_t)(m0 + row) * K + kt * 32 + (lane & 3) * 8,
                  &A_lds[(w * 32 + c * 16) * 32]);
            g2l16(Bt + (size_t)(n0 + row) * K + kt * 32 + (lane & 3) * 8,
                  &B_lds[(w * 32 + c * 16) * 32]);
        }
        __syncthreads();
        bf16x8 af[4], bfr[4];
#pragma unroll
        for (int i = 0; i < 4; i++) {
            af[i]  = ldb8(&A_lds[(wy * 64 + i * 16 + l16) * 32 + quad * 8]);
            bfr[i] = ldb8(&B_lds[(wx * 64 + i * 16 + l16) * 32 + quad * 8]);
        }
#pragma unroll
        for (int mi = 0; mi < 4; mi++)
#pragma unroll
            for (int ni = 0; ni < 4; ni++)
                acc[mi][ni] = __builtin_amdgcn_mfma_f32_16x16x32_bf16(af[mi], bfr[ni], acc[mi][ni], 0, 0, 0);
    }
#pragma unroll
    for (int ni = 0; ni < 4; ni++) {
        int col = n0 + wx * 64 + ni * 16 + l16;
        float bv_ = bias[col];
#pragma unroll
        for (int mi = 0; mi < 4; mi++)
#pragma unroll
            for (int r = 0; r < 4; r++) {
                int row = m0 + wy * 64 + mi * 16 + quad * 4 + r;
                Cout[(size_t)row * N + col] = f2bf(acc[mi][ni][r] + bv_);
            }
    }
}

// ---------------- output GEMM: ctx[4096][1024] @ Wo^T + bo -> out fp32 ----------------
__global__ __launch_bounds__(256) void gemm_out(
    const short* __restrict__ Ab, const short* __restrict__ Bt,
    const float* __restrict__ bias, float* __restrict__ C) {
    const int K = 1024, N = 1024;
    int mt = blockIdx.x, nt = blockIdx.y;
    int tid = threadIdx.x;
    int w = tid >> 6, lane = tid & 63;
    int quad = lane >> 4, l16 = lane & 15;
    int wy = w >> 1, wx = w & 1;

    __shared__ __align__(16) short A_lds[128 * 32];
    __shared__ __align__(16) short B_lds[128 * 32];

    f32x4 acc[4][4];
#pragma unroll
    for (int mi = 0; mi < 4; mi++)
#pragma unroll
        for (int ni = 0; ni < 4; ni++) acc[mi][ni] = (f32x4){0.f, 0.f, 0.f, 0.f};

    int m0 = mt * 128, n0 = nt * 128;
    for (int kt = 0; kt < 32; kt++) {
        __syncthreads();
#pragma unroll
        for (int c = 0; c < 2; c++) {
            int row = w * 32 + c * 16 + (lane >> 2);
            g2l16(Ab + (size_t)(m0 + row) * K + kt * 32 + (lane & 3) * 8,
                  &A_lds[(w * 32 + c * 16) * 32]);
            g2l16(Bt + (size_t)(n0 + row) * K + kt * 32 + (lane & 3) * 8,
                  &B_lds[(w * 32 + c * 16) * 32]);
        }
        __syncthreads();
        bf16x8 af[4], bfr[4];
#pragma unroll
        for (int i = 0; i < 4; i++) {
            af[i]  = ldb8(&A_lds[(wy * 64 + i * 16 + l16) * 32 + quad * 8]);
            bfr[i] = ldb8(&B_lds[(wx * 64 + i * 16 + l16) * 32 + quad * 8]);
        }
#pragma unroll
        for (int mi = 0; mi < 4; mi++)
#pragma unroll
            for (int ni = 0; ni < 4; ni++)
                acc[mi][ni] = __builtin_amdgcn_mfma_f32_16x16x32_bf16(af[mi], bfr[ni], acc[mi][ni], 0, 0, 0);
    }
#pragma unroll
    for (int ni = 0; ni < 4; ni++) {
        int col = n0 + wx * 64 + ni * 16 + l16;
        float bv_ = bias[col];
#pragma unroll
        for (int mi = 0; mi < 4; mi++)
#pragma unroll
            for (int r = 0; r < 4; r++) {
                int row = m0 + wy * 64 + mi * 16 + quad * 4 + r;
                C[(size_t)row * N + col] = acc[mi][ni][r] + bv_;
            }
    }
}

// ---------------- flash attention: Q,K [B*S][E] bf16, VT [bh][64][S] bf16 -> ctx bf16 ----------------
__global__ __launch_bounds__(256) void attn_kernel(
    const short* __restrict__ Qb, const short* __restrict__ Kb,
    const short* __restrict__ VT, const float* __restrict__ mask,
    short* __restrict__ ctx) {
    const int S = 2048, E = 1024, HH = 16;
    int qb = blockIdx.x;
    int h = blockIdx.y;
    int b = blockIdx.z;
    int tid = threadIdx.x;
    int w = tid >> 6, lane = tid & 63;
    int quad = lane >> 4, l16 = lane & 15;

    __shared__ __align__(16) short K_lds[128 * 64];
    __shared__ __align__(16) short VT_lds[64 * 128];
    __shared__ __align__(16) short P_lds[4][32 * 128];

    int q0 = qb * 128;

    bf16x8 qf[2][2];
#pragma unroll
    for (int mi = 0; mi < 2; mi++)
#pragma unroll
        for (int kc = 0; kc < 2; kc++)
            qf[mi][kc] = ldb8(Qb + (size_t)(b * S + q0 + w * 32 + mi * 16 + l16) * E + h * 64 + kc * 32 + quad * 8);

    f32x4 O[2][4];
    float mstate[2][4], lstate[2][4];
#pragma unroll
    for (int mi = 0; mi < 2; mi++) {
#pragma unroll
        for (int nd = 0; nd < 4; nd++) O[mi][nd] = (f32x4){0.f, 0.f, 0.f, 0.f};
#pragma unroll
        for (int r = 0; r < 4; r++) { mstate[mi][r] = -1e30f; lstate[mi][r] = 0.f; }
    }

    const short* Kbase = Kb + (size_t)b * S * E + h * 64;
    const short* Vbase = VT + (size_t)(b * HH + h) * 64 * S;

    for (int kt = 0; kt < 16; kt++) {
        int k0 = kt * 128;
        __syncthreads();
#pragma unroll
        for (int c = 0; c < 4; c++) {
            int row = w * 32 + c * 8 + (lane >> 3);
            g2l16(Kbase + (size_t)(k0 + row) * E + (lane & 7) * 8, &K_lds[(w * 32 + c * 8) * 64]);
        }
#pragma unroll
        for (int c = 0; c < 4; c++) {
            int row = w * 16 + c * 4 + (lane >> 4);
            g2l16(Vbase + (size_t)row * S + k0 + l16 * 8, &VT_lds[(w * 16 + c * 4) * 128]);
        }
        __syncthreads();

        // QK^T
        f32x4 sc[2][8];
#pragma unroll
        for (int mi = 0; mi < 2; mi++)
#pragma unroll
            for (int ni = 0; ni < 8; ni++) sc[mi][ni] = (f32x4){0.f, 0.f, 0.f, 0.f};
#pragma unroll
        for (int ni = 0; ni < 8; ni++) {
            bf16x8 kf0 = ldb8(&K_lds[(ni * 16 + l16) * 64 + quad * 8]);
            bf16x8 kf1 = ldb8(&K_lds[(ni * 16 + l16) * 64 + 32 + quad * 8]);
#pragma unroll
            for (int mi = 0; mi < 2; mi++) {
                sc[mi][ni] = __builtin_amdgcn_mfma_f32_16x16x32_bf16(qf[mi][0], kf0, sc[mi][ni], 0, 0, 0);
                sc[mi][ni] = __builtin_amdgcn_mfma_f32_16x16x32_bf16(qf[mi][1], kf1, sc[mi][ni], 0, 0, 0);
            }
        }
        // scale + mask
        float madd[8];
#pragma unroll
        for (int ni = 0; ni < 8; ni++)
            madd[ni] = (1.0f - mask[b * S + k0 + ni * 16 + l16]) * -10000.0f;
#pragma unroll
        for (int mi = 0; mi < 2; mi++) {
#pragma unroll
            for (int ni = 0; ni < 8; ni++)
#pragma unroll
                for (int r = 0; r < 4; r++)
                    sc[mi][ni][r] = sc[mi][ni][r] * 0.125f + madd[ni];

            float mx[4];
#pragma unroll
            for (int r = 0; r < 4; r++) {
                mx[r] = sc[mi][0][r];
#pragma unroll
                for (int ni = 1; ni < 8; ni++) mx[r] = fmaxf(mx[r], sc[mi][ni][r]);
            }
#pragma unroll
            for (int off = 1; off < 16; off <<= 1)
#pragma unroll
                for (int r = 0; r < 4; r++) mx[r] = fmaxf(mx[r], __shfl_xor(mx[r], off, 64));

            float newm[4], alpha[4], rs[4];
#pragma unroll
            for (int r = 0; r < 4; r++) {
                newm[r] = fmaxf(mstate[mi][r], mx[r]);
                alpha[r] = __expf(mstate[mi][r] - newm[r]);
                mstate[mi][r] = newm[r];
                rs[r] = 0.f;
            }
#pragma unroll
            for (int ni = 0; ni < 8; ni++)
#pragma unroll
                for (int r = 0; r < 4; r++) {
                    float p = __expf(sc[mi][ni][r] - newm[r]);
                    sc[mi][ni][r] = p;
                    rs[r] += p;
                }
#pragma unroll
            for (int off = 1; off < 16; off <<= 1)
#pragma unroll
                for (int r = 0; r < 4; r++) rs[r] += __shfl_xor(rs[r], off, 64);
#pragma unroll
            for (int r = 0; r < 4; r++)
                lstate[mi][r] = lstate[mi][r] * alpha[r] + rs[r];
#pragma unroll
            for (int nd = 0; nd < 4; nd++)
#pragma unroll
                for (int r = 0; r < 4; r++) O[mi][nd][r] *= alpha[r];
            // write P to per-wave LDS (C-layout -> A-layout round-trip)
#pragma unroll
            for (int ni = 0; ni < 8; ni++)
#pragma unroll
                for (int r = 0; r < 4; r++)
                    P_lds[w][(mi * 16 + quad * 4 + r) * 128 + ni * 16 + l16] = f2bf(sc[mi][ni][r]);
        }
        // PV
#pragma unroll
        for (int ks = 0; ks < 4; ks++) {
            bf16x8 pf[2];
#pragma unroll
            for (int mi = 0; mi < 2; mi++)
                pf[mi] = ldb8(&P_lds[w][(mi * 16 + l16) * 128 + ks * 32 + quad * 8]);
#pragma unroll
            for (int nd = 0; nd < 4; nd++) {
                bf16x8 vf = ldb8(&VT_lds[(nd * 16 + l16) * 128 + ks * 32 + quad * 8]);
#pragma unroll
                for (int mi = 0; mi < 2; mi++)
                    O[mi][nd] = __builtin_amdgcn_mfma_f32_16x16x32_bf16(pf[mi], vf, O[mi][nd], 0, 0, 0);
            }
        }
    }
    // epilogue
#pragma unroll
    for (int mi = 0; mi < 2; mi++)
#pragma unroll
        for (int r = 0; r < 4; r++) {
            float l = lstate[mi][r];
            float inv = l > 0.f ? 1.0f / l : 0.f;
            int row = q0 + w * 32 + mi * 16 + quad * 4 + r;
#pragma unroll
            for (int nd = 0; nd < 4; nd++)
                ctx[(size_t)(b * S + row) * E + h * 64 + nd * 16 + l16] = f2bf(O[mi][nd][r] * inv);
        }
}

extern "C" void kernel_launch(void* const* d_in, const int* in_sizes, int n_in,
                              void* d_out, int out_size, void* d_ws, size_t ws_size,
                              hipStream_t stream) {
    const float* X    = (const float*)d_in[0];
    const float* mask = (const float*)d_in[1];
    const float* Wq   = (const float*)d_in[2];
    const float* bq   = (const float*)d_in[3];
    const float* Wk   = (const float*)d_in[4];
    const float* bk   = (const float*)d_in[5];
    const float* Wv   = (const float*)d_in[6];
    const float* bv   = (const float*)d_in[7];
    const float* Wo   = (const float*)d_in[8];
    const float* bo   = (const float*)d_in[9];
    float* out = (float*)d_out;

    char* ws = (char*)d_ws;
    short* Xb  = (short*)(ws);                     // 8 MiB (reused as ctx)
    short* WqT = (short*)(ws + (8u << 20));        // 2 MiB
    short* WkT = (short*)(ws + (10u << 20));
    short* WvT = (short*)(ws + (12u << 20));
    short* WoT = (short*)(ws + (14u << 20));
    short* Qb  = (short*)(ws + (16u << 20));       // 8 MiB
    short* Kb  = (short*)(ws + (24u << 20));       // 8 MiB
    short* Vb  = (short*)(ws + (32u << 20));       // 8 MiB
    short* VT  = (short*)(ws + (40u << 20));       // 8 MiB
    short* ctx = Xb;

    cast_x<<<4096, 256, 0, stream>>>(X, Xb);
    transpose_w<<<dim3(32, 32, 4), 256, 0, stream>>>(Wq, Wk, Wv, Wo, WqT, WkT, WvT, WoT);
    gemm_qkv<<<dim3(32, 24), 256, 0, stream>>>(Xb, WqT, WkT, WvT, bq, bk, bv, Qb, Kb, Vb);
    transpose_v<<<dim3(64, 2, 32), 256, 0, stream>>>(Vb, VT);
    attn_kernel<<<dim3(16, 16, 2), 256, 0, stream>>>(Qb, Kb, VT, mask, ctx);
    gemm_out<<<dim3(32, 8), 256, 0, stream>>>(ctx, WoT, bo, out);
}

// Round 3
// 243.211 us; speedup vs baseline: 1.4647x; 1.4647x over previous
//
#include <hip/hip_runtime.h>
#include <hip/hip_bf16.h>
#include <stdint.h>

typedef __bf16 bf16x8 __attribute__((ext_vector_type(8)));
typedef __bf16 bf16x4_t __attribute__((ext_vector_type(4)));
typedef float  f32x4  __attribute__((ext_vector_type(4)));
typedef short  short8 __attribute__((ext_vector_type(8)));
typedef short  short4v __attribute__((ext_vector_type(4)));
typedef float  float4v __attribute__((ext_vector_type(4)));

#define AS1 __attribute__((address_space(1)))
#define AS3 __attribute__((address_space(3)))

__device__ __forceinline__ void g2l16(const void* g, void* l) {
    __builtin_amdgcn_global_load_lds((const AS1 void*)g, (AS3 void*)l, 16, 0, 0);
}

__device__ __forceinline__ short f2bf(float f) {
    unsigned u = __builtin_bit_cast(unsigned, f);
    unsigned r = u + 0x7FFFu + ((u >> 16) & 1u);
    return (short)(r >> 16);
}

__device__ __forceinline__ bf16x8 ldb8(const short* p) {
    return __builtin_bit_cast(bf16x8, *(const short8*)p);
}

__device__ __forceinline__ float fast_exp2(float x) {
    return __builtin_amdgcn_exp2f(x);
}

// ---------------- cast X fp32 -> bf16 ----------------
__global__ __launch_bounds__(256) void cast_x(const float* __restrict__ X,
                                              short* __restrict__ Xb) {
    int i = (blockIdx.x * 256 + threadIdx.x) * 4;
    float4v v = *(const float4v*)(X + i);
    short4v o;
    o[0] = f2bf(v[0]); o[1] = f2bf(v[1]); o[2] = f2bf(v[2]); o[3] = f2bf(v[3]);
    *(short4v*)(Xb + i) = o;
}

// ---------------- transpose weights: W[K][N] fp32 -> WT[N][K] bf16 ----------------
__global__ __launch_bounds__(256) void transpose_w(
    const float* __restrict__ W0, const float* __restrict__ W1,
    const float* __restrict__ W2, const float* __restrict__ W3,
    short* __restrict__ T0, short* __restrict__ T1,
    short* __restrict__ T2, short* __restrict__ T3) {
    int z = blockIdx.z;
    const float* W = z == 0 ? W0 : z == 1 ? W1 : z == 2 ? W2 : W3;
    short* T = z == 0 ? T0 : z == 1 ? T1 : z == 2 ? T2 : T3;
    __shared__ float t[32][33];
    int n0 = blockIdx.x * 32, k0 = blockIdx.y * 32;
    int tx = threadIdx.x & 31, ty = threadIdx.x >> 5;
#pragma unroll
    for (int i = 0; i < 4; i++)
        t[ty + i * 8][tx] = W[(size_t)(k0 + ty + i * 8) * 1024 + n0 + tx];
    __syncthreads();
#pragma unroll
    for (int i = 0; i < 4; i++)
        T[(size_t)(n0 + ty + i * 8) * 1024 + k0 + tx] = f2bf(t[tx][ty + i * 8]);
}

// ---------------- transpose V: Vb[B*S][E] -> VT[bh][64][S] ----------------
__global__ __launch_bounds__(256) void transpose_v(const short* __restrict__ Vb,
                                                   short* __restrict__ VT) {
    int bh = blockIdx.z;
    int b = bh >> 4, h = bh & 15;
    int d0 = blockIdx.y * 32;
    int s0 = blockIdx.x * 32;
    __shared__ short t[32][33];
    int tx = threadIdx.x & 31, ty = threadIdx.x >> 5;
#pragma unroll
    for (int i = 0; i < 4; i++)
        t[ty + i * 8][tx] = Vb[(size_t)(b * 2048 + s0 + ty + i * 8) * 1024 + h * 64 + d0 + tx];
    __syncthreads();
#pragma unroll
    for (int i = 0; i < 4; i++)
        VT[(size_t)(bh * 64 + d0 + ty + i * 8) * 2048 + s0 + tx] = t[tx][ty + i * 8];
}

// ---------------- fused QKV GEMM: Xb[4096][1024] @ W^T -> {Q,K,V}b bf16 ----------------
__global__ __launch_bounds__(256) void gemm_qkv(
    const short* __restrict__ Xb,
    const short* __restrict__ WqT, const short* __restrict__ WkT, const short* __restrict__ WvT,
    const float* __restrict__ bq, const float* __restrict__ bk, const float* __restrict__ bv,
    short* __restrict__ Qb, short* __restrict__ Kb, short* __restrict__ Vb) {
    const int K = 1024, N = 1024;
    int mt = blockIdx.x;
    int yy = blockIdx.y;
    int mat = yy >> 3, nt = yy & 7;
    const short* Bt = mat == 0 ? WqT : mat == 1 ? WkT : WvT;
    const float* bias = mat == 0 ? bq : mat == 1 ? bk : bv;
    short* Cout = mat == 0 ? Qb : mat == 1 ? Kb : Vb;

    int tid = threadIdx.x;
    int w = tid >> 6, lane = tid & 63;
    int quad = lane >> 4, l16 = lane & 15;
    int wy = w >> 1, wx = w & 1;

    __shared__ __align__(16) short A_lds[128 * 32];
    __shared__ __align__(16) short B_lds[128 * 32];

    f32x4 acc[4][4];
#pragma unroll
    for (int mi = 0; mi < 4; mi++)
#pragma unroll
        for (int ni = 0; ni < 4; ni++) acc[mi][ni] = (f32x4){0.f, 0.f, 0.f, 0.f};

    int m0 = mt * 128, n0 = nt * 128;
    for (int kt = 0; kt < 32; kt++) {
        __syncthreads();
#pragma unroll
        for (int c = 0; c < 2; c++) {
            int row = w * 32 + c * 16 + (lane >> 2);
            g2l16(Xb + (size_t)(m0 + row) * K + kt * 32 + (lane & 3) * 8,
                  &A_lds[(w * 32 + c * 16) * 32]);
            g2l16(Bt + (size_t)(n0 + row) * K + kt * 32 + (lane & 3) * 8,
                  &B_lds[(w * 32 + c * 16) * 32]);
        }
        __syncthreads();
        bf16x8 af[4], bfr[4];
#pragma unroll
        for (int i = 0; i < 4; i++) {
            af[i]  = ldb8(&A_lds[(wy * 64 + i * 16 + l16) * 32 + quad * 8]);
            bfr[i] = ldb8(&B_lds[(wx * 64 + i * 16 + l16) * 32 + quad * 8]);
        }
#pragma unroll
        for (int mi = 0; mi < 4; mi++)
#pragma unroll
            for (int ni = 0; ni < 4; ni++)
                acc[mi][ni] = __builtin_amdgcn_mfma_f32_16x16x32_bf16(af[mi], bfr[ni], acc[mi][ni], 0, 0, 0);
    }
#pragma unroll
    for (int ni = 0; ni < 4; ni++) {
        int col = n0 + wx * 64 + ni * 16 + l16;
        float bv_ = bias[col];
#pragma unroll
        for (int mi = 0; mi < 4; mi++)
#pragma unroll
            for (int r = 0; r < 4; r++) {
                int row = m0 + wy * 64 + mi * 16 + quad * 4 + r;
                Cout[(size_t)row * N + col] = f2bf(acc[mi][ni][r] + bv_);
            }
    }
}

// ---------------- output GEMM: ctx[4096][1024] @ Wo^T + bo -> out fp32 ----------------
__global__ __launch_bounds__(256) void gemm_out(
    const short* __restrict__ Ab, const short* __restrict__ Bt,
    const float* __restrict__ bias, float* __restrict__ C) {
    const int K = 1024, N = 1024;
    int mt = blockIdx.x, nt = blockIdx.y;
    int tid = threadIdx.x;
    int w = tid >> 6, lane = tid & 63;
    int quad = lane >> 4, l16 = lane & 15;
    int wy = w >> 1, wx = w & 1;

    __shared__ __align__(16) short A_lds[128 * 32];
    __shared__ __align__(16) short B_lds[128 * 32];

    f32x4 acc[4][4];
#pragma unroll
    for (int mi = 0; mi < 4; mi++)
#pragma unroll
        for (int ni = 0; ni < 4; ni++) acc[mi][ni] = (f32x4){0.f, 0.f, 0.f, 0.f};

    int m0 = mt * 128, n0 = nt * 128;
    for (int kt = 0; kt < 32; kt++) {
        __syncthreads();
#pragma unroll
        for (int c = 0; c < 2; c++) {
            int row = w * 32 + c * 16 + (lane >> 2);
            g2l16(Ab + (size_t)(m0 + row) * K + kt * 32 + (lane & 3) * 8,
                  &A_lds[(w * 32 + c * 16) * 32]);
            g2l16(Bt + (size_t)(n0 + row) * K + kt * 32 + (lane & 3) * 8,
                  &B_lds[(w * 32 + c * 16) * 32]);
        }
        __syncthreads();
        bf16x8 af[4], bfr[4];
#pragma unroll
        for (int i = 0; i < 4; i++) {
            af[i]  = ldb8(&A_lds[(wy * 64 + i * 16 + l16) * 32 + quad * 8]);
            bfr[i] = ldb8(&B_lds[(wx * 64 + i * 16 + l16) * 32 + quad * 8]);
        }
#pragma unroll
        for (int mi = 0; mi < 4; mi++)
#pragma unroll
            for (int ni = 0; ni < 4; ni++)
                acc[mi][ni] = __builtin_amdgcn_mfma_f32_16x16x32_bf16(af[mi], bfr[ni], acc[mi][ni], 0, 0, 0);
    }
#pragma unroll
    for (int ni = 0; ni < 4; ni++) {
        int col = n0 + wx * 64 + ni * 16 + l16;
        float bv_ = bias[col];
#pragma unroll
        for (int mi = 0; mi < 4; mi++)
#pragma unroll
            for (int r = 0; r < 4; r++) {
                int row = m0 + wy * 64 + mi * 16 + quad * 4 + r;
                C[(size_t)row * N + col] = acc[mi][ni][r] + bv_;
            }
    }
}

// ---------------- flash attention v2: S^T formulation, swizzled LDS ----------------
// Q,K [B*S][E] bf16, VT [bh][64][S] bf16 -> ctx [B*S][E] bf16
// Per block: 128 q rows (qb*128), one (b,h). Per wave: 32 q (w*32 + mi*16 + l16).
// K-tile = 64. S^T = K·Q^T via mfma(kf,qf): C rows=k(quad*4+r), cols=q(l16).
// O^T = V^T·P^T via mfma(vf,pf): C rows=d, cols=q.
#define PROW 72  // P_lds row stride in shorts (64 + 8 pad -> 144B, 8B-aligned, conflict-free)
__global__ __launch_bounds__(256) void attn_kernel(
    const short* __restrict__ Qb, const short* __restrict__ Kb,
    const short* __restrict__ VT, const float* __restrict__ mask,
    short* __restrict__ ctx) {
    const int S = 2048, E = 1024, HH = 16;
    const float LOG2E = 1.44269504f;
    int qb = blockIdx.x;
    int h = blockIdx.y;
    int b = blockIdx.z;
    int tid = threadIdx.x;
    int w = tid >> 6, lane = tid & 63;
    int quad = lane >> 4, l16 = lane & 15;

    __shared__ __align__(16) short K_lds[64 * 64];     // [k=64][d=64], 16B-block xor-swizzled
    __shared__ __align__(16) short VT_lds[64 * 64];    // [d=64][k=64], 16B-block xor-swizzled
    __shared__ __align__(16) short P_lds[4][32 * PROW];

    int q0 = qb * 128;

    // Q fragments (second mfma operand): Q[q = l16 (+16mi)][d = kc*32 + quad*8 + j]
    bf16x8 qf[2][2];
#pragma unroll
    for (int mi = 0; mi < 2; mi++)
#pragma unroll
        for (int kc = 0; kc < 2; kc++)
            qf[mi][kc] = ldb8(Qb + (size_t)(b * S + q0 + w * 32 + mi * 16 + l16) * E + h * 64 + kc * 32 + quad * 8);

    // O^T accumulators: O_t[mi][nd] holds O^T[d = nd*16+quad*4+r][q = mi*16+l16]
    f32x4 O_t[2][4];
    float mstate[2], lstate[2];
#pragma unroll
    for (int mi = 0; mi < 2; mi++) {
#pragma unroll
        for (int nd = 0; nd < 4; nd++) O_t[mi][nd] = (f32x4){0.f, 0.f, 0.f, 0.f};
        mstate[mi] = -1e30f; lstate[mi] = 0.f;
    }

    const short* Kbase = Kb + (size_t)b * S * E + h * 64;
    const short* Vbase = VT + (size_t)(b * HH + h) * 64 * S;
    short* Pw = &P_lds[w][0];

    for (int kt = 0; kt < 32; kt++) {
        int k0 = kt * 64;
        __syncthreads();
        // stage K tile: rows k0..k0+63 of K (d=64 each). xor-swizzle source block.
#pragma unroll
        for (int c = 0; c < 2; c++) {
            int row = w * 16 + c * 8 + (lane >> 3);
            int srcb = (lane & 7) ^ (row & 7);
            g2l16(Kbase + (size_t)(k0 + row) * E + srcb * 8, &K_lds[(w * 16 + c * 8) * 64]);
        }
        // stage V^T tile: rows d=0..63, cols k0..k0+63.
#pragma unroll
        for (int c = 0; c < 2; c++) {
            int row = w * 16 + c * 8 + (lane >> 3);
            int srcb = (lane & 7) ^ (row & 7);
            g2l16(Vbase + (size_t)row * S + k0 + srcb * 8, &VT_lds[(w * 16 + c * 8) * 64]);
        }
        __syncthreads();

        // S^T = K·Q^T : sc[mi][ni] rows k = ni*16+quad*4+r, cols q = mi*16+l16
        f32x4 sc[2][4];
#pragma unroll
        for (int mi = 0; mi < 2; mi++)
#pragma unroll
            for (int ni = 0; ni < 4; ni++) sc[mi][ni] = (f32x4){0.f, 0.f, 0.f, 0.f};
#pragma unroll
        for (int ni = 0; ni < 4; ni++) {
            int rsw = l16 & 7;
#pragma unroll
            for (int kc = 0; kc < 2; kc++) {
                int blk = (kc * 4 + quad) ^ rsw;
                bf16x8 kf = ldb8(&K_lds[(ni * 16 + l16) * 64 + blk * 8]);
#pragma unroll
                for (int mi = 0; mi < 2; mi++)
                    sc[mi][ni] = __builtin_amdgcn_mfma_f32_16x16x32_bf16(kf, qf[mi][kc], sc[mi][ni], 0, 0, 0);
            }
        }

        // scale + mask (exp2 domain): madd[ni][r] depends only on k
        float4v madd[4];
#pragma unroll
        for (int ni = 0; ni < 4; ni++) {
            float4v mrow = *(const float4v*)(mask + b * S + k0 + ni * 16 + quad * 4);
#pragma unroll
            for (int r = 0; r < 4; r++)
                madd[ni][r] = (1.0f - mrow[r]) * (-10000.0f * LOG2E);
        }
        const float SCL = 0.125f * LOG2E;

#pragma unroll
        for (int mi = 0; mi < 2; mi++) {
#pragma unroll
            for (int ni = 0; ni < 4; ni++)
#pragma unroll
                for (int r = 0; r < 4; r++)
                    sc[mi][ni][r] = sc[mi][ni][r] * SCL + madd[ni][r];

            float mx = sc[mi][0][0];
#pragma unroll
            for (int ni = 0; ni < 4; ni++)
#pragma unroll
                for (int r = 0; r < 4; r++) mx = fmaxf(mx, sc[mi][ni][r]);
            mx = fmaxf(mx, __shfl_xor(mx, 16, 64));
            mx = fmaxf(mx, __shfl_xor(mx, 32, 64));

            float newm = fmaxf(mstate[mi], mx);
            float alpha = fast_exp2(mstate[mi] - newm);
            mstate[mi] = newm;

            float rs = 0.f;
#pragma unroll
            for (int ni = 0; ni < 4; ni++)
#pragma unroll
                for (int r = 0; r < 4; r++) {
                    float p = fast_exp2(sc[mi][ni][r] - newm);
                    sc[mi][ni][r] = p;
                    rs += p;
                }
            rs += __shfl_xor(rs, 16, 64);
            rs += __shfl_xor(rs, 32, 64);
            lstate[mi] = lstate[mi] * alpha + rs;
#pragma unroll
            for (int nd = 0; nd < 4; nd++)
#pragma unroll
                for (int r = 0; r < 4; r++) O_t[mi][nd][r] *= alpha;

            // P write: lane holds P[q=mi*16+l16][k=ni*16+quad*4 + r] -> contiguous b64
#pragma unroll
            for (int ni = 0; ni < 4; ni++) {
                bf16x4_t pb = __builtin_convertvector(sc[mi][ni], bf16x4_t);
                *(short4v*)&Pw[(mi * 16 + l16) * PROW + ni * 16 + quad * 4] =
                    __builtin_bit_cast(short4v, pb);
            }
        }

        // O^T += V^T · P^T : mfma(vf[nd][ks], pf[mi][ks])
#pragma unroll
        for (int ks = 0; ks < 2; ks++) {
            bf16x8 pf[2];
#pragma unroll
            for (int mi = 0; mi < 2; mi++)
                pf[mi] = ldb8(&Pw[(mi * 16 + l16) * PROW + ks * 32 + quad * 8]);
            int rsw = l16 & 7;
#pragma unroll
            for (int nd = 0; nd < 4; nd++) {
                int blk = (ks * 4 + quad) ^ rsw;
                bf16x8 vf = ldb8(&VT_lds[(nd * 16 + l16) * 64 + blk * 8]);
#pragma unroll
                for (int mi = 0; mi < 2; mi++)
                    O_t[mi][nd] = __builtin_amdgcn_mfma_f32_16x16x32_bf16(vf, pf[mi], O_t[mi][nd], 0, 0, 0);
            }
        }
    }

    // epilogue: lane holds O^T[d = nd*16+quad*4+r][q = w*32+mi*16+l16] -> 4 consecutive d
#pragma unroll
    for (int mi = 0; mi < 2; mi++) {
        float l = lstate[mi];
        float inv = l > 0.f ? 1.0f / l : 0.f;
        int row = q0 + w * 32 + mi * 16 + l16;
#pragma unroll
        for (int nd = 0; nd < 4; nd++) {
            f32x4 o = O_t[mi][nd];
            f32x4 os = {o[0] * inv, o[1] * inv, o[2] * inv, o[3] * inv};
            bf16x4_t ob = __builtin_convertvector(os, bf16x4_t);
            *(short4v*)&ctx[(size_t)(b * S + row) * E + h * 64 + nd * 16 + quad * 4] =
                __builtin_bit_cast(short4v, ob);
        }
    }
}

extern "C" void kernel_launch(void* const* d_in, const int* in_sizes, int n_in,
                              void* d_out, int out_size, void* d_ws, size_t ws_size,
                              hipStream_t stream) {
    const float* X    = (const float*)d_in[0];
    const float* mask = (const float*)d_in[1];
    const float* Wq   = (const float*)d_in[2];
    const float* bq   = (const float*)d_in[3];
    const float* Wk   = (const float*)d_in[4];
    const float* bk   = (const float*)d_in[5];
    const float* Wv   = (const float*)d_in[6];
    const float* bv   = (const float*)d_in[7];
    const float* Wo   = (const float*)d_in[8];
    const float* bo   = (const float*)d_in[9];
    float* out = (float*)d_out;

    char* ws = (char*)d_ws;
    short* Xb  = (short*)(ws);                     // 8 MiB (reused as ctx)
    short* WqT = (short*)(ws + (8u << 20));        // 2 MiB
    short* WkT = (short*)(ws + (10u << 20));
    short* WvT = (short*)(ws + (12u << 20));
    short* WoT = (short*)(ws + (14u << 20));
    short* Qb  = (short*)(ws + (16u << 20));       // 8 MiB
    short* Kb  = (short*)(ws + (24u << 20));       // 8 MiB
    short* Vb  = (short*)(ws + (32u << 20));       // 8 MiB
    short* VT  = (short*)(ws + (40u << 20));       // 8 MiB
    short* ctx = Xb;

    cast_x<<<4096, 256, 0, stream>>>(X, Xb);
    transpose_w<<<dim3(32, 32, 4), 256, 0, stream>>>(Wq, Wk, Wv, Wo, WqT, WkT, WvT, WoT);
    gemm_qkv<<<dim3(32, 24), 256, 0, stream>>>(Xb, WqT, WkT, WvT, bq, bk, bv, Qb, Kb, Vb);
    transpose_v<<<dim3(64, 2, 32), 256, 0, stream>>>(Vb, VT);
    attn_kernel<<<dim3(16, 16, 2), 256, 0, stream>>>(Qb, Kb, VT, mask, ctx);
    gemm_out<<<dim3(32, 8), 256, 0, stream>>>(ctx, WoT, bo, out);
}

// Round 4
// 219.761 us; speedup vs baseline: 1.6210x; 1.1067x over previous
//
#include <hip/hip_runtime.h>
#include <hip/hip_bf16.h>
#include <stdint.h>

typedef __bf16 bf16x8 __attribute__((ext_vector_type(8)));
typedef __bf16 bf16x4_t __attribute__((ext_vector_type(4)));
typedef float  f32x4  __attribute__((ext_vector_type(4)));
typedef short  short8 __attribute__((ext_vector_type(8)));
typedef short  short4v __attribute__((ext_vector_type(4)));
typedef float  float4v __attribute__((ext_vector_type(4)));

#define AS1 __attribute__((address_space(1)))
#define AS3 __attribute__((address_space(3)))

__device__ __forceinline__ void g2l16(const void* g, void* l) {
    __builtin_amdgcn_global_load_lds((const AS1 void*)g, (AS3 void*)l, 16, 0, 0);
}

__device__ __forceinline__ short f2bf(float f) {
    unsigned u = __builtin_bit_cast(unsigned, f);
    unsigned r = u + 0x7FFFu + ((u >> 16) & 1u);
    return (short)(r >> 16);
}

__device__ __forceinline__ bf16x8 ldb8(const short* p) {
    return __builtin_bit_cast(bf16x8, *(const short8*)p);
}

__device__ __forceinline__ float fast_exp2(float x) {
    return __builtin_amdgcn_exp2f(x);
}

#define LOG2E 1.44269504f
#define QSCL (0.125f * LOG2E)

// ---------------- cast X fp32 -> bf16 ----------------
__global__ __launch_bounds__(256) void cast_x(const float* __restrict__ X,
                                              short* __restrict__ Xb) {
    int i = (blockIdx.x * 256 + threadIdx.x) * 4;
    float4v v = *(const float4v*)(X + i);
    short4v o;
    o[0] = f2bf(v[0]); o[1] = f2bf(v[1]); o[2] = f2bf(v[2]); o[3] = f2bf(v[3]);
    *(short4v*)(Xb + i) = o;
}

// ---------------- transpose weights: W[K][N] fp32 -> WT[N][K] bf16 ----------------
__global__ __launch_bounds__(256) void transpose_w(
    const float* __restrict__ W0, const float* __restrict__ W1,
    const float* __restrict__ W2, const float* __restrict__ W3,
    short* __restrict__ T0, short* __restrict__ T1,
    short* __restrict__ T2, short* __restrict__ T3) {
    int z = blockIdx.z;
    const float* W = z == 0 ? W0 : z == 1 ? W1 : z == 2 ? W2 : W3;
    short* T = z == 0 ? T0 : z == 1 ? T1 : z == 2 ? T2 : T3;
    __shared__ float t[32][33];
    int n0 = blockIdx.x * 32, k0 = blockIdx.y * 32;
    int tx = threadIdx.x & 31, ty = threadIdx.x >> 5;
#pragma unroll
    for (int i = 0; i < 4; i++)
        t[ty + i * 8][tx] = W[(size_t)(k0 + ty + i * 8) * 1024 + n0 + tx];
    __syncthreads();
#pragma unroll
    for (int i = 0; i < 4; i++)
        T[(size_t)(n0 + ty + i * 8) * 1024 + k0 + tx] = f2bf(t[tx][ty + i * 8]);
}

// ---------------- fused QKV GEMM: Xb[4096][1024] @ W^T -> Qb(prescaled), Kb, VT ----------
// Q written with *QSCL (attention consumes exp2-domain scores directly).
// V written TRANSPOSED into VT[bh][d=64][s=2048] (lane's 4 consecutive m-rows = 4
// consecutive s -> contiguous b64 store).
__global__ __launch_bounds__(256) void gemm_qkv(
    const short* __restrict__ Xb,
    const short* __restrict__ WqT, const short* __restrict__ WkT, const short* __restrict__ WvT,
    const float* __restrict__ bq, const float* __restrict__ bk, const float* __restrict__ bv,
    short* __restrict__ Qb, short* __restrict__ Kb, short* __restrict__ VT) {
    const int K = 1024, N = 1024;
    int mt = blockIdx.x;
    int yy = blockIdx.y;
    int mat = yy >> 3, nt = yy & 7;
    const short* Bt = mat == 0 ? WqT : mat == 1 ? WkT : WvT;
    const float* bias = mat == 0 ? bq : mat == 1 ? bk : bv;

    int tid = threadIdx.x;
    int w = tid >> 6, lane = tid & 63;
    int quad = lane >> 4, l16 = lane & 15;
    int wy = w >> 1, wx = w & 1;

    __shared__ __align__(16) short A_lds[128 * 32];
    __shared__ __align__(16) short B_lds[128 * 32];

    f32x4 acc[4][4];
#pragma unroll
    for (int mi = 0; mi < 4; mi++)
#pragma unroll
        for (int ni = 0; ni < 4; ni++) acc[mi][ni] = (f32x4){0.f, 0.f, 0.f, 0.f};

    int m0 = mt * 128, n0 = nt * 128;
    for (int kt = 0; kt < 32; kt++) {
        __syncthreads();
#pragma unroll
        for (int c = 0; c < 2; c++) {
            int row = w * 32 + c * 16 + (lane >> 2);
            g2l16(Xb + (size_t)(m0 + row) * K + kt * 32 + (lane & 3) * 8,
                  &A_lds[(w * 32 + c * 16) * 32]);
            g2l16(Bt + (size_t)(n0 + row) * K + kt * 32 + (lane & 3) * 8,
                  &B_lds[(w * 32 + c * 16) * 32]);
        }
        __syncthreads();
        bf16x8 af[4], bfr[4];
#pragma unroll
        for (int i = 0; i < 4; i++) {
            af[i]  = ldb8(&A_lds[(wy * 64 + i * 16 + l16) * 32 + quad * 8]);
            bfr[i] = ldb8(&B_lds[(wx * 64 + i * 16 + l16) * 32 + quad * 8]);
        }
#pragma unroll
        for (int mi = 0; mi < 4; mi++)
#pragma unroll
            for (int ni = 0; ni < 4; ni++)
                acc[mi][ni] = __builtin_amdgcn_mfma_f32_16x16x32_bf16(af[mi], bfr[ni], acc[mi][ni], 0, 0, 0);
    }

    if (mat < 2) {
        short* Cout = mat == 0 ? Qb : Kb;
        float s = mat == 0 ? QSCL : 1.0f;
#pragma unroll
        for (int ni = 0; ni < 4; ni++) {
            int col = n0 + wx * 64 + ni * 16 + l16;
            float bv_ = bias[col];
#pragma unroll
            for (int mi = 0; mi < 4; mi++)
#pragma unroll
                for (int r = 0; r < 4; r++) {
                    int row = m0 + wy * 64 + mi * 16 + quad * 4 + r;
                    Cout[(size_t)row * N + col] = f2bf((acc[mi][ni][r] + bv_) * s);
                }
        }
    } else {
        // V: write transposed. col = h*64+d, rows are tokens (b*2048+s).
#pragma unroll
        for (int ni = 0; ni < 4; ni++) {
            int col = n0 + wx * 64 + ni * 16 + l16;
            float bv_ = bias[col];
#pragma unroll
            for (int mi = 0; mi < 4; mi++) {
                int row0 = m0 + wy * 64 + mi * 16 + quad * 4;  // 4 consecutive tokens
                int bb = row0 >> 11, ss = row0 & 2047;
                f32x4 a = acc[mi][ni];
                f32x4 av = {a[0] + bv_, a[1] + bv_, a[2] + bv_, a[3] + bv_};
                bf16x4_t ob = __builtin_convertvector(av, bf16x4_t);
                *(short4v*)&VT[((size_t)(bb * 16) << 17) + ((size_t)col * 2048) + ss] =
                    __builtin_bit_cast(short4v, ob);
            }
        }
    }
}

// ---------------- output GEMM: ctx[4096][1024] @ Wo^T + bo -> out fp32 (64x128 tiles) ----
__global__ __launch_bounds__(256) void gemm_out(
    const short* __restrict__ Ab, const short* __restrict__ Bt,
    const float* __restrict__ bias, float* __restrict__ C) {
    const int K = 1024, N = 1024;
    int mt = blockIdx.x, nt = blockIdx.y;
    int tid = threadIdx.x;
    int w = tid >> 6, lane = tid & 63;
    int quad = lane >> 4, l16 = lane & 15;

    __shared__ __align__(16) short A_lds[64 * 32];
    __shared__ __align__(16) short B_lds[128 * 32];

    f32x4 acc[4][2];
#pragma unroll
    for (int mi = 0; mi < 4; mi++)
#pragma unroll
        for (int ni = 0; ni < 2; ni++) acc[mi][ni] = (f32x4){0.f, 0.f, 0.f, 0.f};

    int m0 = mt * 64, n0 = nt * 128;
    for (int kt = 0; kt < 32; kt++) {
        __syncthreads();
        {
            int row = w * 16 + (lane >> 2);
            g2l16(Ab + (size_t)(m0 + row) * K + kt * 32 + (lane & 3) * 8,
                  &A_lds[(w * 16) * 32]);
        }
#pragma unroll
        for (int c = 0; c < 2; c++) {
            int row = w * 32 + c * 16 + (lane >> 2);
            g2l16(Bt + (size_t)(n0 + row) * K + kt * 32 + (lane & 3) * 8,
                  &B_lds[(w * 32 + c * 16) * 32]);
        }
        __syncthreads();
        bf16x8 af[4], bfr[2];
#pragma unroll
        for (int i = 0; i < 4; i++)
            af[i] = ldb8(&A_lds[(i * 16 + l16) * 32 + quad * 8]);
#pragma unroll
        for (int i = 0; i < 2; i++)
            bfr[i] = ldb8(&B_lds[(w * 32 + i * 16 + l16) * 32 + quad * 8]);
#pragma unroll
        for (int mi = 0; mi < 4; mi++)
#pragma unroll
            for (int ni = 0; ni < 2; ni++)
                acc[mi][ni] = __builtin_amdgcn_mfma_f32_16x16x32_bf16(af[mi], bfr[ni], acc[mi][ni], 0, 0, 0);
    }
#pragma unroll
    for (int ni = 0; ni < 2; ni++) {
        int col = n0 + w * 32 + ni * 16 + l16;
        float bv_ = bias[col];
#pragma unroll
        for (int mi = 0; mi < 4; mi++)
#pragma unroll
            for (int r = 0; r < 4; r++) {
                int row = m0 + mi * 16 + quad * 4 + r;
                C[(size_t)row * N + col] = acc[mi][ni][r] + bv_;
            }
    }
}

// ---------------- flash attention v3: 512 threads, 8 waves x 16q, S^T form ----------------
#define PROW 72  // P_lds row stride in shorts (conflict-free at b64/b128 BW floor)
__global__ __launch_bounds__(512) void attn_kernel(
    const short* __restrict__ Qb, const short* __restrict__ Kb,
    const short* __restrict__ VT, const float* __restrict__ mask,
    short* __restrict__ ctx) {
    const int S = 2048, E = 1024, HH = 16;
    int qb = blockIdx.x;
    int h = blockIdx.y;
    int b = blockIdx.z;
    int tid = threadIdx.x;
    int w = tid >> 6, lane = tid & 63;
    int quad = lane >> 4, l16 = lane & 15;

    __shared__ __align__(16) short K_lds[64 * 64];
    __shared__ __align__(16) short VT_lds[64 * 64];
    __shared__ __align__(16) short P_lds[8][16 * PROW];
    __shared__ int maskflag;

    if (tid == 0) maskflag = 1;
    __syncthreads();
    {
        float4v m = *(const float4v*)(mask + b * S + tid * 4);
        if (!(m[0] == 1.f && m[1] == 1.f && m[2] == 1.f && m[3] == 1.f))
            maskflag = 0;
    }
    __syncthreads();
    const bool nomask = (maskflag != 0);

    int q0 = qb * 128;

    // Q fragments (pre-scaled by QSCL in gemm_qkv)
    bf16x8 qf[2];
#pragma unroll
    for (int kc = 0; kc < 2; kc++)
        qf[kc] = ldb8(Qb + (size_t)(b * S + q0 + w * 16 + l16) * E + h * 64 + kc * 32 + quad * 8);

    f32x4 O_t[4];
    float mstate = -1e30f, lstate = 0.f;
#pragma unroll
    for (int nd = 0; nd < 4; nd++) O_t[nd] = (f32x4){0.f, 0.f, 0.f, 0.f};

    const short* Kbase = Kb + (size_t)b * S * E + h * 64;
    const short* Vbase = VT + (size_t)(b * HH + h) * 64 * S;
    short* Pw = &P_lds[w][0];
    int rsw = l16 & 7;

    for (int kt = 0; kt < 32; kt++) {
        int k0 = kt * 64;
        __syncthreads();
        {
            int row = w * 8 + (lane >> 3);
            int srcb = (lane & 7) ^ (row & 7);
            g2l16(Kbase + (size_t)(k0 + row) * E + srcb * 8, &K_lds[(w * 8) * 64]);
            g2l16(Vbase + (size_t)row * S + k0 + srcb * 8, &VT_lds[(w * 8) * 64]);
        }
        __syncthreads();

        // S^T = K·Q^T : sc[ni] rows k = ni*16+quad*4+r, cols q = l16
        f32x4 sc[4];
#pragma unroll
        for (int ni = 0; ni < 4; ni++) sc[ni] = (f32x4){0.f, 0.f, 0.f, 0.f};
#pragma unroll
        for (int ni = 0; ni < 4; ni++) {
#pragma unroll
            for (int kc = 0; kc < 2; kc++) {
                int blk = (kc * 4 + quad) ^ rsw;
                bf16x8 kf = ldb8(&K_lds[(ni * 16 + l16) * 64 + blk * 8]);
                sc[ni] = __builtin_amdgcn_mfma_f32_16x16x32_bf16(kf, qf[kc], sc[ni], 0, 0, 0);
            }
        }

        if (!nomask) {
#pragma unroll
            for (int ni = 0; ni < 4; ni++) {
                float4v mrow = *(const float4v*)(mask + b * S + k0 + ni * 16 + quad * 4);
#pragma unroll
                for (int r = 0; r < 4; r++)
                    sc[ni][r] += (1.0f - mrow[r]) * (-10000.0f * LOG2E);
            }
        }

        float mx = sc[0][0];
#pragma unroll
        for (int ni = 0; ni < 4; ni++)
#pragma unroll
            for (int r = 0; r < 4; r++) mx = fmaxf(mx, sc[ni][r]);
        mx = fmaxf(mx, __shfl_xor(mx, 16, 64));
        mx = fmaxf(mx, __shfl_xor(mx, 32, 64));

        float newm = fmaxf(mstate, mx);
        float alpha = fast_exp2(mstate - newm);
        mstate = newm;

        float rs = 0.f;
#pragma unroll
        for (int ni = 0; ni < 4; ni++)
#pragma unroll
            for (int r = 0; r < 4; r++) {
                float p = fast_exp2(sc[ni][r] - newm);
                sc[ni][r] = p;
                rs += p;
            }
        rs += __shfl_xor(rs, 16, 64);
        rs += __shfl_xor(rs, 32, 64);
        lstate = lstate * alpha + rs;
#pragma unroll
        for (int nd = 0; nd < 4; nd++)
#pragma unroll
            for (int r = 0; r < 4; r++) O_t[nd][r] *= alpha;

        // P write: lane holds P[q=l16][k=ni*16+quad*4 + r] -> contiguous b64
#pragma unroll
        for (int ni = 0; ni < 4; ni++) {
            bf16x4_t pb = __builtin_convertvector(sc[ni], bf16x4_t);
            *(short4v*)&Pw[l16 * PROW + ni * 16 + quad * 4] =
                __builtin_bit_cast(short4v, pb);
        }

        // O^T += V^T · P^T
#pragma unroll
        for (int ks = 0; ks < 2; ks++) {
            bf16x8 pf = ldb8(&Pw[l16 * PROW + ks * 32 + quad * 8]);
#pragma unroll
            for (int nd = 0; nd < 4; nd++) {
                int blk = (ks * 4 + quad) ^ rsw;
                bf16x8 vf = ldb8(&VT_lds[(nd * 16 + l16) * 64 + blk * 8]);
                O_t[nd] = __builtin_amdgcn_mfma_f32_16x16x32_bf16(vf, pf, O_t[nd], 0, 0, 0);
            }
        }
    }

    // epilogue
    {
        float l = lstate;
        float inv = l > 0.f ? 1.0f / l : 0.f;
        int row = q0 + w * 16 + l16;
#pragma unroll
        for (int nd = 0; nd < 4; nd++) {
            f32x4 o = O_t[nd];
            f32x4 os = {o[0] * inv, o[1] * inv, o[2] * inv, o[3] * inv};
            bf16x4_t ob = __builtin_convertvector(os, bf16x4_t);
            *(short4v*)&ctx[(size_t)(b * S + row) * E + h * 64 + nd * 16 + quad * 4] =
                __builtin_bit_cast(short4v, ob);
        }
    }
}

extern "C" void kernel_launch(void* const* d_in, const int* in_sizes, int n_in,
                              void* d_out, int out_size, void* d_ws, size_t ws_size,
                              hipStream_t stream) {
    const float* X    = (const float*)d_in[0];
    const float* mask = (const float*)d_in[1];
    const float* Wq   = (const float*)d_in[2];
    const float* bq   = (const float*)d_in[3];
    const float* Wk   = (const float*)d_in[4];
    const float* bk   = (const float*)d_in[5];
    const float* Wv   = (const float*)d_in[6];
    const float* bv   = (const float*)d_in[7];
    const float* Wo   = (const float*)d_in[8];
    const float* bo   = (const float*)d_in[9];
    float* out = (float*)d_out;

    char* ws = (char*)d_ws;
    short* Xb  = (short*)(ws);                     // 8 MiB (reused as ctx)
    short* WqT = (short*)(ws + (8u << 20));        // 2 MiB
    short* WkT = (short*)(ws + (10u << 20));
    short* WvT = (short*)(ws + (12u << 20));
    short* WoT = (short*)(ws + (14u << 20));
    short* Qb  = (short*)(ws + (16u << 20));       // 8 MiB
    short* Kb  = (short*)(ws + (24u << 20));       // 8 MiB
    short* VT  = (short*)(ws + (32u << 20));       // 8 MiB, V stored transposed [bh][64][2048]
    short* ctx = Xb;

    cast_x<<<4096, 256, 0, stream>>>(X, Xb);
    transpose_w<<<dim3(32, 32, 4), 256, 0, stream>>>(Wq, Wk, Wv, Wo, WqT, WkT, WvT, WoT);
    gemm_qkv<<<dim3(32, 24), 256, 0, stream>>>(Xb, WqT, WkT, WvT, bq, bk, bv, Qb, Kb, VT);
    attn_kernel<<<dim3(16, 16, 2), 512, 0, stream>>>(Qb, Kb, VT, mask, ctx);
    gemm_out<<<dim3(64, 8), 256, 0, stream>>>(ctx, WoT, bo, out);
}